// Round 2
// baseline (971.854 us; speedup 1.0000x reference)
//
#include <hip/hip_runtime.h>
#include <math.h>

#define HIDDEN 4096
#define NEXP   64
#define NTOK   16384
#define NW     8                  // waves per block = k-chunks (MUST stay 8: numerics)
#define KC     (HIDDEN / NW)      // 512 k per chunk
#define BK     16                 // k per LDS stage
#define ITERS  (KC / BK)          // 32
#define XST    66                 // padded LDS row stride (floats) for x tiles

// ---------- Kernel 0: transpose W (1 MB) into workspace: Wt[k][e] = W[e][k] ----------
__global__ void wtrans(const float* __restrict__ W, float* __restrict__ Wt) {
    const int k  = blockIdx.x * 64 + (threadIdx.x & 63);
    const int e0 = threadIdx.x >> 6;                       // 0..3
#pragma unroll
    for (int ee = 0; ee < 64; ee += 4)                     // coalesced reads along k
        Wt[(size_t)k * NEXP + (ee + e0)] = W[(size_t)(ee + e0) * HIDDEN + k];
}

// ---------- Kernel 1: fused gating ----------
// Block = 64 tokens, 8 waves; wave c owns k-chunk [c*512, c*512+512).
// lane = token; acc[64] = one partial logit per expert (W wave-uniform -> SGPRs).
// Per k: 1 ds_read_b32 (x) + 64 v_fmac with scalar W operand -> pure-VALU stream.
__global__ __launch_bounds__(512, 2)
void gating_main(const float* __restrict__ x, const float* __restrict__ Wt,
                 const float* __restrict__ bias, float* __restrict__ out) {
    __shared__ float smem[16384];   // 64 KB union: Xc tiles (8 x [16][66]) | red (swizzled)

    const int tid  = threadIdx.x;
    const int lane = tid & 63;
    const int wid  = __builtin_amdgcn_readfirstlane(tid >> 6);  // uniform wave id = chunk
    const int t0   = blockIdx.x * 64;

    float acc[64];
#pragma unroll
    for (int e = 0; e < 64; ++e) acc[e] = 0.f;

    float* Xc = smem + wid * (BK * XST);   // this wave's private staging tile [BK][XST]
    const int sg = lane & 3;               // 4-float k-group 0..3
    const int sr = lane >> 2;              // token row 0..15 (+16 per pass)
    const int kbase = wid * KC;

    // prologue: stage iter 0 (coalesced: 16 rows x 64B segments per pass)
    float4 nv[4];
#pragma unroll
    for (int p = 0; p < 4; ++p)
        nv[p] = *(const float4*)&x[(size_t)(t0 + p * 16 + sr) * HIDDEN + kbase + sg * 4];
#pragma unroll
    for (int p = 0; p < 4; ++p) {
        const int r = p * 16 + sr;
        Xc[(sg * 4 + 0) * XST + r] = nv[p].x;
        Xc[(sg * 4 + 1) * XST + r] = nv[p].y;
        Xc[(sg * 4 + 2) * XST + r] = nv[p].z;
        Xc[(sg * 4 + 3) * XST + r] = nv[p].w;
    }

    for (int it = 0; it < ITERS; ++it) {
        const int k0 = kbase + it * BK;
        // prefetch next tile to registers (HBM latency hides under the FMA block)
        if (it + 1 < ITERS) {
#pragma unroll
            for (int p = 0; p < 4; ++p)
                nv[p] = *(const float4*)&x[(size_t)(t0 + p * 16 + sr) * HIDDEN + k0 + BK + sg * 4];
        }
        // compute: k ascending (exact fmaf chain preserved per (token, expert))
#pragma unroll
        for (int kk = 0; kk < BK; ++kk) {
            const float xv = Xc[kk * XST + lane];                 // 2-way alias: free
            const float* __restrict__ wr = Wt + (size_t)(k0 + kk) * NEXP;  // uniform -> s_load
#pragma unroll
            for (int e = 0; e < 64; ++e)
                acc[e] = fmaf(xv, wr[e], acc[e]);
        }
        // write next tile (per-wave DS ordering makes WAR with reads above safe; no barrier)
        if (it + 1 < ITERS) {
#pragma unroll
            for (int p = 0; p < 4; ++p) {
                const int r = p * 16 + sr;
                Xc[(sg * 4 + 0) * XST + r] = nv[p].x;
                Xc[(sg * 4 + 1) * XST + r] = nv[p].y;
                Xc[(sg * 4 + 2) * XST + r] = nv[p].z;
                Xc[(sg * 4 + 3) * XST + r] = nv[p].w;
            }
        }
    }

    // ---------- epilogue: cross-wave 8-chunk reduce + softmax + top-2 ----------
    // red layout (XOR-swizzled, 64 KB exactly): red[(c*32 + t)*64 + (e ^ t)]
    //   stores: lanes vary t, e static  -> banks = low5(e)^t : conflict-free
    //   loads : lanes vary e, t fixed   -> 2-way : free
    __syncthreads();                       // all waves done with Xc (smem reused)
    float* red = smem;
    const int hl = lane >> 5;              // token half this lane belongs to
    const int tl = lane & 31;

#pragma unroll
    for (int ph = 0; ph < 2; ++ph) {
        if (hl == ph) {
#pragma unroll
            for (int ee = 0; ee < 64; ++ee)                    // static acc index
                red[((wid * 32 + tl) << 6) | (ee ^ tl)] = acc[ee];
        }
        __syncthreads();

#pragma unroll
        for (int q = 0; q < 4; ++q) {
            const int tt = wid * 4 + q;    // 0..31 within this phase

            float l = bias[lane];
#pragma unroll
            for (int c = 0; c < NW; ++c)   // chunk order 0..7, same as before
                l += red[((c * 32 + tt) << 6) | (lane ^ tt)];

            // wave max
            float mx = l;
#pragma unroll
            for (int s = 32; s > 0; s >>= 1)
                mx = fmaxf(mx, __shfl_xor(mx, s, 64));

            // softmax denominator (deterministic butterfly)
            float ssum = expf(l - mx);
#pragma unroll
            for (int s = 32; s > 0; s >>= 1)
                ssum += __shfl_xor(ssum, s, 64);

            // top-1: max value, lower index wins ties
            float v1 = l; int i1 = lane;
#pragma unroll
            for (int s = 32; s > 0; s >>= 1) {
                float ov = __shfl_xor(v1, s, 64);
                int   oi = __shfl_xor(i1, s, 64);
                if (ov > v1 || (ov == v1 && oi < i1)) { v1 = ov; i1 = oi; }
            }
            // top-2: exclude i1
            float v2 = (lane == i1) ? -INFINITY : l;
            int   i2 = lane;
#pragma unroll
            for (int s = 32; s > 0; s >>= 1) {
                float ov = __shfl_xor(v2, s, 64);
                int   oi = __shfl_xor(i2, s, 64);
                if (ov > v2 || (ov == v2 && oi < i2)) { v2 = ov; i2 = oi; }
            }

            if (lane == 0) {
                const int t = t0 + ph * 32 + tt;
                const float inv = 1.0f / ssum;
                out[(size_t)t * 2 + 0] = inv;                   // exp(v1-mx)=1 since v1==mx
                out[(size_t)t * 2 + 1] = expf(v2 - mx) * inv;
                out[(size_t)2 * NTOK + t * 2 + 0] = (float)i1;  // indices read back as float32
                out[(size_t)2 * NTOK + t * 2 + 1] = (float)i2;
            }
        }
        __syncthreads();   // phase 1 rewrites red only after phase-0 reads complete
    }
}

extern "C" void kernel_launch(void* const* d_in, const int* in_sizes, int n_in,
                              void* d_out, int out_size, void* d_ws, size_t ws_size,
                              hipStream_t stream) {
    const float* x = (const float*)d_in[0];
    const float* W = (const float*)d_in[1];
    const float* b = (const float*)d_in[2];
    float* out = (float*)d_out;
    float* Wt  = (float*)d_ws;    // 4096*64*4 = 1 MB scratch

    wtrans<<<dim3(HIDDEN / 64), 256, 0, stream>>>(W, Wt);
    gating_main<<<dim3(NTOK / 64), 512, 0, stream>>>(x, Wt, b, out);
}

// Round 3
// 707.908 us; speedup vs baseline: 1.3729x; 1.3729x over previous
//
#include <hip/hip_runtime.h>
#include <math.h>

#define HIDDEN   4096
#define NEXP     64
#define NTOK     16384
#define KCHUNKS  8
#define KC       (HIDDEN / KCHUNKS)   // 512 k per chunk
#define BK       16                   // k per LDS stage
#define ITERS    (KC / BK)            // 32
#define BT       64                   // tokens per block

// ---------------- Kernel 1: split-K fp32 GEMM -> partial logits ----------------
// grid (256 token tiles, 8 k-chunks), block = 64 threads (1 wave, NO barriers).
// LDS double-buffered via global_load_lds_dwordx4 (linear dest), XOR-swizzled
// row-major tiles: element (row r, k q) at word r*16 + 4*((q>>2) ^ (r>>3 & 3)) + (q&3).
//   - staging: dest linear (lane*16B), source global address pre-swizzled
//   - compute: ds_read_b128 at swizzled word; 8 distinct rows -> 4 banks = 2-way (free)
// Per-lane 8x8 tile: per 4-k group, 16 ds_read_b128 -> 256 FMA (VALU-dominant).
// fmaf chain per (token, expert): k ascending 0..511 within chunk — bit-identical
// to the round-0 kernel that passed with absmax 0.0.
__global__ __launch_bounds__(64, 2)
void gemm_partial(const float* __restrict__ x, const float* __restrict__ W,
                  float* __restrict__ part) {
    __shared__ float lds[2][2][64 * BK];   // [buf][X=0/W=1][swizzled 64xBK] = 16 KB

    const int lane = threadIdx.x;
    const int tile = blockIdx.x;       // token tile 0..255
    const int kc   = blockIdx.y;       // k chunk 0..7
    const int t0   = tile * BT;
    const int i    = lane & 7;         // token group (8 tokens)
    const int j    = lane >> 3;        // expert group (8 experts)
    const int kbase = kc * KC;

    // staging source pointers, instr p: row = p*16 + (lane>>2),
    // k-offset = 4*((lane&3) ^ ((2p + (lane>>5)) & 3))  [= inverse of the LDS swizzle]
    const float* xsrc[4];
    const float* wsrc[4];
#pragma unroll
    for (int p = 0; p < 4; ++p) {
        const int row = p * 16 + (lane >> 2);
        const int kk  = 4 * ((lane & 3) ^ ((2 * p + (lane >> 5)) & 3));
        xsrc[p] = &x[(size_t)(t0 + row) * HIDDEN + kbase + kk];
        wsrc[p] = &W[(size_t)row * HIDDEN + kbase + kk];
    }

#define STAGE(buf, itn) do {                                                        \
    _Pragma("unroll")                                                               \
    for (int p = 0; p < 4; ++p) {                                                   \
        __builtin_amdgcn_global_load_lds(                                           \
            (const __attribute__((address_space(1))) uint32_t*)(xsrc[p] + (itn) * BK), \
            (__attribute__((address_space(3))) uint32_t*)&lds[buf][0][p * 256],     \
            16, 0, 0);                                                              \
        __builtin_amdgcn_global_load_lds(                                           \
            (const __attribute__((address_space(1))) uint32_t*)(wsrc[p] + (itn) * BK), \
            (__attribute__((address_space(3))) uint32_t*)&lds[buf][1][p * 256],     \
            16, 0, 0);                                                              \
    }                                                                               \
} while (0)

    float acc[8][8];
#pragma unroll
    for (int m = 0; m < 8; ++m)
#pragma unroll
        for (int e = 0; e < 8; ++e) acc[m][e] = 0.f;

    STAGE(0, 0);

#pragma unroll 2
    for (int it = 0; it < ITERS; ++it) {
        const int cb = it & 1;
        const int nb = cb ^ 1;
#pragma unroll
        for (int g = 0; g < 4; ++g) {       // 4-k groups; k = it*16 + g*4 + dk, ascending
            float4 xv[8], wv[8];
#pragma unroll
            for (int m = 0; m < 8; ++m)
                xv[m] = *(const float4*)&lds[cb][0][(i * 8 + m) * BK + ((g * 4) ^ ((i & 3) << 2))];
#pragma unroll
            for (int e = 0; e < 8; ++e)
                wv[e] = *(const float4*)&lds[cb][1][(j * 8 + e) * BK + ((g * 4) ^ ((j & 3) << 2))];
            // issue next-tile staging after this tile's first reads, before the FMA wall:
            // its ~900cy latency hides under ~2048cy of FMA issue.
            if (g == 0 && it + 1 < ITERS) STAGE(nb, it + 1);
#pragma unroll
            for (int dk = 0; dk < 4; ++dk)
#pragma unroll
                for (int m = 0; m < 8; ++m) {
                    const float xs = ((const float*)&xv[m])[dk];
#pragma unroll
                    for (int e = 0; e < 8; ++e)
                        acc[m][e] = fmaf(xs, ((const float*)&wv[e])[dk], acc[m][e]);
                }
        }
    }
#undef STAGE

    // write partial logits: part[kc][token][expert]  (identical to round-0)
    float* dst = part + ((size_t)kc * NTOK + t0) * NEXP;
#pragma unroll
    for (int m = 0; m < 8; ++m) {
        const int tok = i * 8 + m;
#pragma unroll
        for (int h = 0; h < 2; ++h) {
            float4 o = make_float4(acc[m][h * 4 + 0], acc[m][h * 4 + 1],
                                   acc[m][h * 4 + 2], acc[m][h * 4 + 3]);
            *(float4*)&dst[(size_t)tok * NEXP + j * 8 + h * 4] = o;
        }
    }
}

// ---------------- Kernel 2: reduce partials + bias, softmax, top-2 ----------------
// One wave per token; lane = expert. Butterfly reductions, tie-break lower index.
// Byte-identical to the round-0 version (passed, absmax 0.0).
__global__ __launch_bounds__(256)
void softmax_top2(const float* __restrict__ part, const float* __restrict__ bias,
                  float* __restrict__ out) {
    const int lane = threadIdx.x & 63;
    const int wid  = threadIdx.x >> 6;
    const int t    = blockIdx.x * 4 + wid;

    float l = bias[lane];
#pragma unroll
    for (int c = 0; c < KCHUNKS; ++c)
        l += part[((size_t)c * NTOK + t) * NEXP + lane];

    // wave max
    float m = l;
#pragma unroll
    for (int s = 32; s > 0; s >>= 1)
        m = fmaxf(m, __shfl_xor(m, s, 64));

    // softmax denominator (deterministic butterfly)
    float ssum = expf(l - m);
#pragma unroll
    for (int s = 32; s > 0; s >>= 1)
        ssum += __shfl_xor(ssum, s, 64);

    // top-1: max value, lower index wins ties
    float v1 = l; int i1 = lane;
#pragma unroll
    for (int s = 32; s > 0; s >>= 1) {
        float ov = __shfl_xor(v1, s, 64);
        int   oi = __shfl_xor(i1, s, 64);
        if (ov > v1 || (ov == v1 && oi < i1)) { v1 = ov; i1 = oi; }
    }
    // top-2: exclude i1
    float v2 = (lane == i1) ? -INFINITY : l;
    int   i2 = lane;
#pragma unroll
    for (int s = 32; s > 0; s >>= 1) {
        float ov = __shfl_xor(v2, s, 64);
        int   oi = __shfl_xor(i2, s, 64);
        if (ov > v2 || (ov == v2 && oi < i2)) { v2 = ov; i2 = oi; }
    }

    if (lane == 0) {
        const float inv = 1.0f / ssum;
        out[(size_t)t * 2 + 0] = inv;                    // exp(v1-m)=1 since v1==m
        out[(size_t)t * 2 + 1] = expf(v2 - m) * inv;
        out[(size_t)2 * NTOK + t * 2 + 0] = (float)i1;   // indices read back as float32
        out[(size_t)2 * NTOK + t * 2 + 1] = (float)i2;
    }
}

extern "C" void kernel_launch(void* const* d_in, const int* in_sizes, int n_in,
                              void* d_out, int out_size, void* d_ws, size_t ws_size,
                              hipStream_t stream) {
    const float* x  = (const float*)d_in[0];
    const float* W  = (const float*)d_in[1];
    const float* b  = (const float*)d_in[2];
    float* out  = (float*)d_out;
    float* part = (float*)d_ws;   // KCHUNKS*NTOK*NEXP*4 = 32 MB scratch

    dim3 g1(NTOK / BT, KCHUNKS);  // 256 x 8 = 2048 one-wave blocks (8 per CU)
    gemm_partial<<<g1, 64, 0, stream>>>(x, W, part);
    softmax_top2<<<NTOK / 4, 256, 0, stream>>>(part, b, out);
}

// Round 4
// 411.257 us; speedup vs baseline: 2.3631x; 1.7213x over previous
//
#include <hip/hip_runtime.h>
#include <math.h>

#define HIDDEN   4096
#define NEXP     64
#define NTOK     16384
#define KCHUNKS  8
#define KC       (HIDDEN / KCHUNKS)   // 512 k per chunk
#define BK       16                   // k per LDS stage
#define ITERS    (KC / BK)            // 32
#define BT       64                   // tokens per block

// ---------------- Kernel 1: split-K fp32 GEMM -> partial logits ----------------
// grid (256 token tiles, 8 k-chunks), block = 64 threads (1 wave).
// Tiles staged with global_load_lds_dwordx4 (linear dest), row-major XOR-swizzled:
//   element (row r, k = 4G+dk) at word r*16 + 4*(G ^ ((r>>3)&3)) + dk.
//   - staging dest linear (lane*16B); source k-offset pre-swizzled (rule: both sides)
//   - compute ds_read_b128: per instr 8 distinct rows -> 4 bank-quads x 2-way = free
// Register hygiene (round-3 spill fix): operands via float4 MEMBERS only, no
// address-of into register arrays, no persistent pointer arrays. ~115 VGPR.
// fmaf chain per (token,expert): k ascending 0..511 within chunk — bit-identical
// to the round-0 kernel (passed, absmax 0.0).
__global__ __launch_bounds__(64, 2)
void gemm_partial(const float* __restrict__ x, const float* __restrict__ W,
                  float* __restrict__ part) {
    __shared__ float lds[2][2][64 * BK];   // [buf][X=0/W=1][64 rows x 16 words] = 16 KB

    const int lane = threadIdx.x;
    const int t0   = blockIdx.x * BT;
    const int kbase = blockIdx.y * KC;
    const int i = lane & 7;            // token group (8 tokens)
    const int j = lane >> 3;           // expert group (8 experts)

    // staging lane offsets (dwords): instr p covers rows p*16 + (lane>>2);
    // source k-offset = 4*((lane&3) ^ ((2p + (lane>>5)) & 3)) — only p parity matters
    const int srow = lane >> 2;                                   // 0..15
    const int sevn = 4 * ((lane & 3) ^ ((lane >> 5) & 3));        // p = 0, 2
    const int sodd = 4 * ((lane & 3) ^ ((2 + (lane >> 5)) & 3));  // p = 1, 3

#define STAGE(buf, itn) do {                                                          \
    _Pragma("unroll")                                                                 \
    for (int p = 0; p < 4; ++p) {                                                     \
        const int ko = kbase + (itn) * BK + ((p & 1) ? sodd : sevn);                  \
        __builtin_amdgcn_global_load_lds(                                             \
            (const __attribute__((address_space(1))) uint32_t*)                       \
                (x + (size_t)(t0 + p * 16 + srow) * HIDDEN + ko),                     \
            (__attribute__((address_space(3))) uint32_t*)&lds[buf][0][p * 256],       \
            16, 0, 0);                                                                \
        __builtin_amdgcn_global_load_lds(                                             \
            (const __attribute__((address_space(1))) uint32_t*)                       \
                (W + (size_t)(p * 16 + srow) * HIDDEN + ko),                          \
            (__attribute__((address_space(3))) uint32_t*)&lds[buf][1][p * 256],       \
            16, 0, 0);                                                                \
    }                                                                                 \
} while (0)

    float acc[8][8];
#pragma unroll
    for (int m = 0; m < 8; ++m)
#pragma unroll
        for (int e = 0; e < 8; ++e) acc[m][e] = 0.f;

    STAGE(0, 0);
    __syncthreads();   // 1-wave block: just the vmcnt drain

    for (int it = 0; it < ITERS; ++it) {
        const int cb = it & 1;
        if (it + 1 < ITERS) STAGE(cb ^ 1, it + 1);   // ~2048 FMA-issue cycles of cover

#pragma unroll
        for (int g = 0; g < 4; ++g) {                // k = it*16 + g*4 + dk, ascending
            float4 WV[8];
#pragma unroll
            for (int e = 0; e < 8; ++e)
                WV[e] = *(const float4*)&lds[cb][1][(j * 8 + e) * BK + 4 * (g ^ (j & 3))];
#pragma unroll
            for (int m = 0; m < 8; ++m) {
                const float4 xq = *(const float4*)&lds[cb][0][(i * 8 + m) * BK + 4 * (g ^ (i & 3))];
#pragma unroll
                for (int e = 0; e < 8; ++e) {
                    float a = fmaf(xq.x, WV[e].x, acc[m][e]);
                    a       = fmaf(xq.y, WV[e].y, a);
                    a       = fmaf(xq.z, WV[e].z, a);
                    acc[m][e] = fmaf(xq.w, WV[e].w, a);
                }
            }
        }
        __syncthreads();   // drains the prefetch before next tile's reads
    }
#undef STAGE

    // write partial logits: part[kc][token][expert]  (identical to round-0)
    float* dst = part + ((size_t)blockIdx.y * NTOK + t0) * NEXP;
#pragma unroll
    for (int m = 0; m < 8; ++m) {
        const int tok = i * 8 + m;
#pragma unroll
        for (int h = 0; h < 2; ++h) {
            float4 o = make_float4(acc[m][h * 4 + 0], acc[m][h * 4 + 1],
                                   acc[m][h * 4 + 2], acc[m][h * 4 + 3]);
            *(float4*)&dst[(size_t)tok * NEXP + j * 8 + h * 4] = o;
        }
    }
}

// ---------------- Kernel 2: reduce partials + bias, softmax, top-2 ----------------
// Byte-identical to the round-0 version (passed, absmax 0.0).
__global__ __launch_bounds__(256)
void softmax_top2(const float* __restrict__ part, const float* __restrict__ bias,
                  float* __restrict__ out) {
    const int lane = threadIdx.x & 63;
    const int wid  = threadIdx.x >> 6;
    const int t    = blockIdx.x * 4 + wid;

    float l = bias[lane];
#pragma unroll
    for (int c = 0; c < KCHUNKS; ++c)
        l += part[((size_t)c * NTOK + t) * NEXP + lane];

    // wave max
    float m = l;
#pragma unroll
    for (int s = 32; s > 0; s >>= 1)
        m = fmaxf(m, __shfl_xor(m, s, 64));

    // softmax denominator (deterministic butterfly)
    float ssum = expf(l - m);
#pragma unroll
    for (int s = 32; s > 0; s >>= 1)
        ssum += __shfl_xor(ssum, s, 64);

    // top-1: max value, lower index wins ties
    float v1 = l; int i1 = lane;
#pragma unroll
    for (int s = 32; s > 0; s >>= 1) {
        float ov = __shfl_xor(v1, s, 64);
        int   oi = __shfl_xor(i1, s, 64);
        if (ov > v1 || (ov == v1 && oi < i1)) { v1 = ov; i1 = oi; }
    }
    // top-2: exclude i1
    float v2 = (lane == i1) ? -INFINITY : l;
    int   i2 = lane;
#pragma unroll
    for (int s = 32; s > 0; s >>= 1) {
        float ov = __shfl_xor(v2, s, 64);
        int   oi = __shfl_xor(i2, s, 64);
        if (ov > v2 || (ov == v2 && oi < i2)) { v2 = ov; i2 = oi; }
    }

    if (lane == 0) {
        const float inv = 1.0f / ssum;
        out[(size_t)t * 2 + 0] = inv;                    // exp(v1-m)=1 since v1==m
        out[(size_t)t * 2 + 1] = expf(v2 - m) * inv;
        out[(size_t)2 * NTOK + t * 2 + 0] = (float)i1;   // indices read back as float32
        out[(size_t)2 * NTOK + t * 2 + 1] = (float)i2;
    }
}

extern "C" void kernel_launch(void* const* d_in, const int* in_sizes, int n_in,
                              void* d_out, int out_size, void* d_ws, size_t ws_size,
                              hipStream_t stream) {
    const float* x  = (const float*)d_in[0];
    const float* W  = (const float*)d_in[1];
    const float* b  = (const float*)d_in[2];
    float* out  = (float*)d_out;
    float* part = (float*)d_ws;   // KCHUNKS*NTOK*NEXP*4 = 32 MB scratch

    dim3 g1(NTOK / BT, KCHUNKS);  // 256 x 8 = 2048 one-wave blocks (8 per CU)
    gemm_partial<<<g1, 64, 0, stream>>>(x, W, part);
    softmax_top2<<<NTOK / 4, 256, 0, stream>>>(part, b, out);
}